// Round 1
// baseline (418.406 us; speedup 1.0000x reference)
//
#include <hip/hip_runtime.h>
#include <hip/hip_bf16.h>
#include <math.h>

// CFConv: out[a][f] = sum_n x[nbr[a][n]][f] * W[a][n][f]
//   W = (softplus(rbf @ w1 + b1)) @ w2 + b2
// N=20000 atoms, NB=32 neighbors, F=128, RBF=64.
//
// R8: swap GEMM1 operands (A=w1^T from the SAME w1f prepack, B=rbf^T from the
// SAME per-lane rbf loads) so H comes out f-major per lane:
//  - H staging: 8x ds_write_b64 + 8x ds_read_b64 per half (was 32x b16 + 4x b128),
//    XOR swizzle blk^ln^((ln&2)<<3) keeps write/read conflicts at the cheap level.
//  - GEMM2 stays normal orientation; W stays ENTIRELY in registers (was 32x b16
//    write + 16x b32 read per half). Epilogue: lane (q,ln) gathers
//    x[j_{q*4+r}][nt*16+ln] (64B-coalesced per 16-lane group) and FMAs against
//    acc[nt][r]; final 2-step shfl_xor reduce over q-groups per atom.
//  - x gathers decoupled from GEMM2: r=0 batch issued before the MFMA cluster,
//    r=1..3 software-pipelined (8-reg double buffer; NO whole-tile prefetch --
//    that spilled in R6).
//  - b1*log2e folded into GEMM1 C-init (reloaded per-half from L1-hot global),
//    b2 splat folded into GEMM2 C-init.
// LDS ops/atom 168 -> 32. LDS total still exactly 80 KB -> 2 blocks/CU.

#define NB     32
#define FD     128
#define RD     64
#define WAVES  8
#define NTILES 2500   // 20000 / 8

#define LOG2E 1.4426950408889634f
#define LN2   0.6931471805599453f

typedef short  short8  __attribute__((ext_vector_type(8)));
typedef float  floatx4 __attribute__((ext_vector_type(4)));
typedef float  floatx2 __attribute__((ext_vector_type(2)));
typedef int    intx4   __attribute__((ext_vector_type(4)));

#define LDS_FENCE() asm volatile("" ::: "memory")  // compiler-only ordering

static __device__ __forceinline__ unsigned pk2(float a, float b) {
  // packed fp32->bf16 RNE (v_cvt_pk_bf16_f32 on gfx950); low 16 = a
  __hip_bfloat162 h = __float22bfloat162_rn(float2{a, b});
  unsigned u;
  __builtin_memcpy(&u, &h, sizeof(u));
  return u;
}

// log2-domain softplus: log2e folded into GEMM1 operands, ln2 into w2.
static __device__ __forceinline__ float sp2(float acc) {
  return __builtin_amdgcn_logf(1.0f + __builtin_amdgcn_exp2f(acc));
}

__global__ __launch_bounds__(512, 4)  // 4 waves/EU = 2 blocks/CU (<=128 regs/wave)
void cfconv_kernel(const float* __restrict__ x,
                   const float* __restrict__ rbf,
                   const int*   __restrict__ nbr,
                   const float* __restrict__ w1,
                   const float* __restrict__ b1,
                   const float* __restrict__ w2,
                   const float* __restrict__ b2,
                   float* __restrict__ out) {
  // operand-fragment layout (A and B identical on gfx950 16x16x32):
  // frag[kt*8+nt][lane][j] = M[kt*32 + (lane>>4)*8 + j][nt*16 + (lane&15)]
  __shared__ __align__(16) short w1f[16][64][8];        // 16 KB (w1, doubles as w1^T A-frags)
  __shared__ __align__(16) short w2f[32][64][8];        // 32 KB
  // per-wave H band: 16 rows (neighbors) x 32 8B-blocks (128 bf16 f's), swizzled
  __shared__ __align__(16) unsigned long long hb[WAVES][16][32]; // 32 KB -> 80 KB total

  const int tid  = threadIdx.x;
  const int lane = tid & 63;
  const int wv   = tid >> 6;
  const int q    = lane >> 4;   // k-quad (A/B) or row-quad (C)
  const int ln   = lane & 15;   // non-K index inside a 16-tile

  // ---- prepack weights (with scale folding) -> bf16 frags in LDS ----
  for (int i = tid; i < RD * FD; i += 512) {
    int k = i >> 7, n = i & 127, kk = k & 31;
    w1f[(k >> 5) * 8 + (n >> 4)][(kk >> 3) * 16 + (n & 15)][kk & 7] =
        (short)pk2(w1[i] * LOG2E, 0.f);
  }
  for (int i = tid; i < FD * FD; i += 512) {
    int k = i >> 7, n = i & 127, kk = k & 31;
    w2f[(k >> 5) * 8 + (n >> 4)][(kk >> 3) * 16 + (n & 15)][kk & 7] =
        (short)pk2(w2[i] * LN2, 0.f);
  }
  float b2v[8];
#pragma unroll
  for (int nt = 0; nt < 8; ++nt) b2v[nt] = b2[nt * 16 + ln];
  __syncthreads();  // the only barrier; hb use below is wave-private

  unsigned long long (*band)[32] = hb[wv];
  const int swz = ln ^ ((ln & 2) << 3);   // 8B-block XOR swizzle term

  for (int tile = blockIdx.x; tile < NTILES; tile += gridDim.x) {
    const int atom = tile * WAVES + wv;
    const int prow = atom * NB;
    const int* nbp = nbr + prow;

    float o[8];
#pragma unroll
    for (int nt = 0; nt < 8; ++nt) o[nt] = 0.f;

#pragma unroll
    for (int mt = 0; mt < 2; ++mt) {
      // neighbor indices: lane (q,ln) owns n = q*4+r of this half
      const intx4 nbi = *(const intx4*)(nbp + mt * 16 + q * 4);

      // ---- rbf B-frags (B = rbf^T: col n = ln, k = kt*32+q*8+j); streamed once ----
      const float* src = rbf + (size_t)(prow + mt * 16 + ln) * RD + q * 8;
      short8 bfr[2];
#pragma unroll
      for (int kt = 0; kt < 2; ++kt) {
        floatx4 lo = __builtin_nontemporal_load((const floatx4*)(src + kt * 32));
        floatx4 hi = __builtin_nontemporal_load((const floatx4*)(src + kt * 32 + 4));
        union { short8 s8; unsigned u[4]; } f;
        f.u[0] = pk2(lo[0], lo[1]);
        f.u[1] = pk2(lo[2], lo[3]);
        f.u[2] = pk2(hi[0], hi[1]);
        f.u[3] = pk2(hi[2], hi[3]);
        bfr[kt] = f.s8;
      }

      // ---- GEMM1 (swapped): C = w1^T @ rbf^T; C-init = b1*log2e (L1-hot reload) ----
      floatx4 acc[8];
#pragma unroll
      for (int nt = 0; nt < 8; ++nt) {
        floatx4 bv = *(const floatx4*)(b1 + nt * 16 + q * 4);
        acc[nt] = floatx4{bv[0] * LOG2E, bv[1] * LOG2E, bv[2] * LOG2E, bv[3] * LOG2E};
      }
#pragma unroll
      for (int kt = 0; kt < 2; ++kt)
#pragma unroll
        for (int nt = 0; nt < 8; ++nt) {
          short8 afr = *(const short8*)&w1f[kt * 8 + nt][lane][0];
          acc[nt] = __builtin_amdgcn_mfma_f32_16x16x32_bf16(afr, bfr[kt], acc[nt], 0, 0, 0);
        }

      // ---- softplus + pack; lane holds H[n=ln][f=nt*16+q*4+r] -> b64 writes ----
#pragma unroll
      for (int nt = 0; nt < 8; ++nt) {
        unsigned u0 = pk2(sp2(acc[nt][0]), sp2(acc[nt][1]));
        unsigned u1 = pk2(sp2(acc[nt][2]), sp2(acc[nt][3]));
        unsigned long long v = (unsigned long long)u0 | ((unsigned long long)u1 << 32);
        band[ln][(nt * 4 + q) ^ swz] = v;
      }
      LDS_FENCE();  // H writes precede hfr reads in program order

      // ---- GEMM2 A-frags: row ln, f = kt*32+q*8..+7 -> blocks kt*8+q*2, +1 ----
      short8 hfr[4];
#pragma unroll
      for (int kt = 0; kt < 4; ++kt) {
        union { short8 s8; unsigned long long d[2]; } f;
        f.d[0] = band[ln][(kt * 8 + q * 2)     ^ swz];
        f.d[1] = band[ln][(kt * 8 + q * 2 + 1) ^ swz];
        hfr[kt] = f.s8;
      }
      LDS_FENCE();  // hfr reads precede next half's band overwrite

      // pre-issue r=0 gather batch: hides under the MFMA cluster
      const float* xb0 = x + (size_t)nbi[0] * FD + ln;
      float xa[8], xc[8];
#pragma unroll
      for (int nt = 0; nt < 8; ++nt) xa[nt] = xb0[nt * 16];

      // ---- GEMM2: W = H @ (ln2*w2); C-init = b2 splat; W stays in registers ----
#pragma unroll
      for (int nt = 0; nt < 8; ++nt)
        acc[nt] = floatx4{b2v[nt], b2v[nt], b2v[nt], b2v[nt]};
#pragma unroll
      for (int kt = 0; kt < 4; ++kt)
#pragma unroll
        for (int nt = 0; nt < 8; ++nt) {
          short8 bfr2 = *(const short8*)&w2f[kt * 8 + nt][lane][0];
          acc[nt] = __builtin_amdgcn_mfma_f32_16x16x32_bf16(hfr[kt], bfr2, acc[nt], 0, 0, 0);
        }

      // ---- epilogue, software-pipelined: o[nt] += x[j_r][nt*16+ln] * acc[nt][r] ----
      const float* xb1 = x + (size_t)nbi[1] * FD + ln;
#pragma unroll
      for (int nt = 0; nt < 8; ++nt) xc[nt] = xb1[nt * 16];
#pragma unroll
      for (int nt = 0; nt < 8; ++nt) o[nt] = fmaf(xa[nt], acc[nt][0], o[nt]);

      const float* xb2 = x + (size_t)nbi[2] * FD + ln;
#pragma unroll
      for (int nt = 0; nt < 8; ++nt) xa[nt] = xb2[nt * 16];
#pragma unroll
      for (int nt = 0; nt < 8; ++nt) o[nt] = fmaf(xc[nt], acc[nt][1], o[nt]);

      const float* xb3 = x + (size_t)nbi[3] * FD + ln;
#pragma unroll
      for (int nt = 0; nt < 8; ++nt) xc[nt] = xb3[nt * 16];
#pragma unroll
      for (int nt = 0; nt < 8; ++nt) o[nt] = fmaf(xa[nt], acc[nt][2], o[nt]);

#pragma unroll
      for (int nt = 0; nt < 8; ++nt) o[nt] = fmaf(xc[nt], acc[nt][3], o[nt]);
    }

    // ---- reduce over the 4 q-groups (n = q*4+r partials) and store ----
#pragma unroll
    for (int nt = 0; nt < 8; ++nt) {
      o[nt] += __shfl_xor(o[nt], 16);
      o[nt] += __shfl_xor(o[nt], 32);
    }
    // lane (q,ln) stores f = q*32+ln and q*32+16+ln (static indexing only)
    float s0 = o[0], s1 = o[1];
    if (q == 1) { s0 = o[2]; s1 = o[3]; }
    if (q == 2) { s0 = o[4]; s1 = o[5]; }
    if (q == 3) { s0 = o[6]; s1 = o[7]; }
    float* op = out + (size_t)atom * FD + q * 32 + ln;
    __builtin_nontemporal_store(s0, op);
    __builtin_nontemporal_store(s1, op + 16);
  }
}

extern "C" void kernel_launch(void* const* d_in, const int* in_sizes, int n_in,
                              void* d_out, int out_size, void* d_ws, size_t ws_size,
                              hipStream_t stream) {
  const float* x   = (const float*)d_in[0];
  const float* rbf = (const float*)d_in[1];
  const int*   nbr = (const int*)d_in[2];
  const float* w1  = (const float*)d_in[3];
  const float* b1  = (const float*)d_in[4];
  const float* w2  = (const float*)d_in[5];
  const float* b2  = (const float*)d_in[6];
  float* out = (float*)d_out;

  // 80 KB LDS -> 2 blocks/CU. 500 blocks x 5 tiles each: exact, all co-resident.
  cfconv_kernel<<<dim3(500), dim3(512), 0, stream>>>(x, rbf, nbr, w1, b1, w2, b2, out);
}

// Round 2
// 375.911 us; speedup vs baseline: 1.1130x; 1.1130x over previous
//
#include <hip/hip_runtime.h>
#include <hip/hip_bf16.h>
#include <math.h>

// CFConv: out[a][f] = sum_n x[nbr[a][n]][f] * W[a][n][f]
//   W = (softplus(rbf @ w1 + b1)) @ w2 + b2
// N=20000 atoms, NB=32 neighbors, F=128, RBF=64.
//
// R9 = R8 (swapped GEMM1, register-resident W) with the spill fixed.
// R8 spilled (WRITE_SIZE 165MB vs 10MB output, VGPR_Count 64, MfmaUtil 5%):
// acc(32) + hfr(16) + xa/xc(16) + b2v(8) all live through GEMM2 exceeded the
// arch-VGPR partition. R9 cuts peak liveness:
//  - hfr is STREAMED per kt inside the GEMM2 loop (8 regs, short lifetime)
//    instead of preloaded as hfr[4] (16 regs spanning the gather pre-issue).
//  - b2 reloaded per half from global (L1-hot) instead of 8 persistent regs.
//  - GEMM1 temporaries scoped so they die before GEMM2.
// Everything else identical to R8 (which was numerically correct):
//  - GEMM1 computes w1^T @ rbf^T so H lands f-major per lane; H staging is
//    8x ds_write_b64 + 8x ds_read_b64 per half, XOR swizzle blk^ln^((ln&2)<<3).
//  - GEMM2 output W stays entirely in registers; epilogue: lane (q,ln)
//    gathers x[j_{q*4+r}][nt*16+ln] and FMAs against acc[nt][r]; 2-step
//    shfl_xor reduce over q-groups.
//  - b1*log2e folded into GEMM1 C-init, b2 into GEMM2 C-init; log2-domain
//    softplus with scales folded into the bf16 weights.

#define NB     32
#define FD     128
#define RD     64
#define WAVES  8
#define NTILES 2500   // 20000 / 8

#define LOG2E 1.4426950408889634f
#define LN2   0.6931471805599453f

typedef short  short8  __attribute__((ext_vector_type(8)));
typedef float  floatx4 __attribute__((ext_vector_type(4)));
typedef float  floatx2 __attribute__((ext_vector_type(2)));
typedef int    intx4   __attribute__((ext_vector_type(4)));

#define LDS_FENCE() asm volatile("" ::: "memory")  // compiler-only ordering

static __device__ __forceinline__ unsigned pk2(float a, float b) {
  // packed fp32->bf16 RNE (v_cvt_pk_bf16_f32 on gfx950); low 16 = a
  __hip_bfloat162 h = __float22bfloat162_rn(float2{a, b});
  unsigned u;
  __builtin_memcpy(&u, &h, sizeof(u));
  return u;
}

// log2-domain softplus: log2e folded into GEMM1 operands, ln2 into w2.
static __device__ __forceinline__ float sp2(float acc) {
  return __builtin_amdgcn_logf(1.0f + __builtin_amdgcn_exp2f(acc));
}

__global__ __launch_bounds__(512, 4)  // 4 waves/EU = 2 blocks/CU (<=128 regs/wave)
void cfconv_kernel(const float* __restrict__ x,
                   const float* __restrict__ rbf,
                   const int*   __restrict__ nbr,
                   const float* __restrict__ w1,
                   const float* __restrict__ b1,
                   const float* __restrict__ w2,
                   const float* __restrict__ b2,
                   float* __restrict__ out) {
  // operand-fragment layout (A and B identical on gfx950 16x16x32):
  // frag[kt*8+nt][lane][j] = M[kt*32 + (lane>>4)*8 + j][nt*16 + (lane&15)]
  __shared__ __align__(16) short w1f[16][64][8];        // 16 KB (w1^T A-frags)
  __shared__ __align__(16) short w2f[32][64][8];        // 32 KB
  // per-wave H band: 16 rows (neighbors) x 32 8B-blocks (128 bf16 f's), swizzled
  __shared__ __align__(16) unsigned long long hb[WAVES][16][32]; // 32 KB -> 80 KB total

  const int tid  = threadIdx.x;
  const int lane = tid & 63;
  const int wv   = tid >> 6;
  const int q    = lane >> 4;   // k-quad (A/B) or row-quad (C)
  const int ln   = lane & 15;   // non-K index inside a 16-tile

  // ---- prepack weights (with scale folding) -> bf16 frags in LDS ----
  for (int i = tid; i < RD * FD; i += 512) {
    int k = i >> 7, n = i & 127, kk = k & 31;
    w1f[(k >> 5) * 8 + (n >> 4)][(kk >> 3) * 16 + (n & 15)][kk & 7] =
        (short)pk2(w1[i] * LOG2E, 0.f);
  }
  for (int i = tid; i < FD * FD; i += 512) {
    int k = i >> 7, n = i & 127, kk = k & 31;
    w2f[(k >> 5) * 8 + (n >> 4)][(kk >> 3) * 16 + (n & 15)][kk & 7] =
        (short)pk2(w2[i] * LN2, 0.f);
  }
  __syncthreads();  // the only barrier; hb use below is wave-private

  unsigned long long (*band)[32] = hb[wv];
  const int swz = ln ^ ((ln & 2) << 3);   // 8B-block XOR swizzle term

  for (int tile = blockIdx.x; tile < NTILES; tile += gridDim.x) {
    const int atom = tile * WAVES + wv;
    const int prow = atom * NB;
    const int* nbp = nbr + prow;

    float o[8];
#pragma unroll
    for (int nt = 0; nt < 8; ++nt) o[nt] = 0.f;

#pragma unroll
    for (int mt = 0; mt < 2; ++mt) {
      // neighbor indices: lane (q,ln) owns n = q*4+r of this half
      const intx4 nbi = *(const intx4*)(nbp + mt * 16 + q * 4);

      floatx4 acc[8];

      { // ---- GEMM1 scope: temporaries die before GEMM2 ----
        // rbf B-frags (B = rbf^T: col n = ln, k = kt*32+q*8+j); streamed once
        const float* src = rbf + (size_t)(prow + mt * 16 + ln) * RD + q * 8;
        short8 bfr[2];
#pragma unroll
        for (int kt = 0; kt < 2; ++kt) {
          floatx4 lo = __builtin_nontemporal_load((const floatx4*)(src + kt * 32));
          floatx4 hi = __builtin_nontemporal_load((const floatx4*)(src + kt * 32 + 4));
          union { short8 s8; unsigned u[4]; } f;
          f.u[0] = pk2(lo[0], lo[1]);
          f.u[1] = pk2(lo[2], lo[3]);
          f.u[2] = pk2(hi[0], hi[1]);
          f.u[3] = pk2(hi[2], hi[3]);
          bfr[kt] = f.s8;
        }

        // C = w1^T @ rbf^T; C-init = b1*log2e (L1-hot reload)
#pragma unroll
        for (int nt = 0; nt < 8; ++nt) {
          floatx4 bv = *(const floatx4*)(b1 + nt * 16 + q * 4);
          acc[nt] = floatx4{bv[0] * LOG2E, bv[1] * LOG2E, bv[2] * LOG2E, bv[3] * LOG2E};
        }
#pragma unroll
        for (int kt = 0; kt < 2; ++kt)
#pragma unroll
          for (int nt = 0; nt < 8; ++nt) {
            short8 afr = *(const short8*)&w1f[kt * 8 + nt][lane][0];
            acc[nt] = __builtin_amdgcn_mfma_f32_16x16x32_bf16(afr, bfr[kt], acc[nt], 0, 0, 0);
          }
      }

      // ---- softplus + pack; lane holds H[n=ln][f=nt*16+q*4+r] -> b64 writes ----
#pragma unroll
      for (int nt = 0; nt < 8; ++nt) {
        unsigned u0 = pk2(sp2(acc[nt][0]), sp2(acc[nt][1]));
        unsigned u1 = pk2(sp2(acc[nt][2]), sp2(acc[nt][3]));
        unsigned long long v = (unsigned long long)u0 | ((unsigned long long)u1 << 32);
        band[ln][(nt * 4 + q) ^ swz] = v;
      }
      LDS_FENCE();  // H writes precede hfr reads in program order

      // pre-issue r=0 gather batch: hides under the LDS reads + MFMA cluster
      const float* xb0 = x + (size_t)nbi[0] * FD + ln;
      float xa[8], xc[8];
#pragma unroll
      for (int nt = 0; nt < 8; ++nt) xa[nt] = xb0[nt * 16];

      // ---- GEMM2: W = H @ (ln2*w2); C-init = b2 splat (L1-hot reload);
      //      hfr streamed per kt (8 regs, short lifetime); W stays in registers.
#pragma unroll
      for (int nt = 0; nt < 8; ++nt) {
        float bb = b2[nt * 16 + ln];
        acc[nt] = floatx4{bb, bb, bb, bb};
      }
#pragma unroll
      for (int kt = 0; kt < 4; ++kt) {
        union { short8 s8; unsigned long long d[2]; } f;
        f.d[0] = band[ln][(kt * 8 + q * 2)     ^ swz];
        f.d[1] = band[ln][(kt * 8 + q * 2 + 1) ^ swz];
        const short8 hk = f.s8;
#pragma unroll
        for (int nt = 0; nt < 8; ++nt) {
          short8 bfr2 = *(const short8*)&w2f[kt * 8 + nt][lane][0];
          acc[nt] = __builtin_amdgcn_mfma_f32_16x16x32_bf16(hk, bfr2, acc[nt], 0, 0, 0);
        }
      }
      LDS_FENCE();  // all band reads precede next half's H overwrite

      // ---- epilogue, 2-deep pipelined: o[nt] += x[j_r][nt*16+ln] * acc[nt][r] ----
      const float* xb1 = x + (size_t)nbi[1] * FD + ln;
#pragma unroll
      for (int nt = 0; nt < 8; ++nt) xc[nt] = xb1[nt * 16];
#pragma unroll
      for (int nt = 0; nt < 8; ++nt) o[nt] = fmaf(xa[nt], acc[nt][0], o[nt]);

      const float* xb2 = x + (size_t)nbi[2] * FD + ln;
#pragma unroll
      for (int nt = 0; nt < 8; ++nt) xa[nt] = xb2[nt * 16];
#pragma unroll
      for (int nt = 0; nt < 8; ++nt) o[nt] = fmaf(xc[nt], acc[nt][1], o[nt]);

      const float* xb3 = x + (size_t)nbi[3] * FD + ln;
#pragma unroll
      for (int nt = 0; nt < 8; ++nt) xc[nt] = xb3[nt * 16];
#pragma unroll
      for (int nt = 0; nt < 8; ++nt) o[nt] = fmaf(xa[nt], acc[nt][2], o[nt]);

#pragma unroll
      for (int nt = 0; nt < 8; ++nt) o[nt] = fmaf(xc[nt], acc[nt][3], o[nt]);
    }

    // ---- reduce over the 4 q-groups (n = q*4+r partials) and store ----
#pragma unroll
    for (int nt = 0; nt < 8; ++nt) {
      o[nt] += __shfl_xor(o[nt], 16);
      o[nt] += __shfl_xor(o[nt], 32);
    }
    // lane (q,ln) stores f = q*32+ln and q*32+16+ln (static indexing only)
    float s0 = o[0], s1 = o[1];
    if (q == 1) { s0 = o[2]; s1 = o[3]; }
    if (q == 2) { s0 = o[4]; s1 = o[5]; }
    if (q == 3) { s0 = o[6]; s1 = o[7]; }
    float* op = out + (size_t)atom * FD + q * 32 + ln;
    __builtin_nontemporal_store(s0, op);
    __builtin_nontemporal_store(s1, op + 16);
  }
}

extern "C" void kernel_launch(void* const* d_in, const int* in_sizes, int n_in,
                              void* d_out, int out_size, void* d_ws, size_t ws_size,
                              hipStream_t stream) {
  const float* x   = (const float*)d_in[0];
  const float* rbf = (const float*)d_in[1];
  const int*   nbr = (const int*)d_in[2];
  const float* w1  = (const float*)d_in[3];
  const float* b1  = (const float*)d_in[4];
  const float* w2  = (const float*)d_in[5];
  const float* b2  = (const float*)d_in[6];
  float* out = (float*)d_out;

  // 80 KB LDS -> 2 blocks/CU. 500 blocks x 5 tiles each: exact, all co-resident.
  cfconv_kernel<<<dim3(500), dim3(512), 0, stream>>>(x, rbf, nbr, w1, b1, w2, b2, out);
}

// Round 3
// 312.496 us; speedup vs baseline: 1.3389x; 1.2029x over previous
//
#include <hip/hip_runtime.h>
#include <hip/hip_bf16.h>
#include <math.h>

// CFConv: out[a][f] = sum_n x[nbr[a][n]][f] * W[a][n][f]
//   W = (softplus(rbf @ w1 + b1)) @ w2 + b2
// N=20000 atoms, NB=32 neighbors, F=128, RBF=64.
//
// R10 = R9 with ONE change: __launch_bounds__(512, 2) instead of (512, 4).
// R8/R9 both spilled (WRITE_SIZE 189MB vs 10MB output, VGPR_Count locked at
// 64, MfmaUtil 6%): the min-4-waves/EU bound caps the unified VGPR file at
// 128/wave, and with MFMA present the backend splits it 64 arch + 64 accum.
// The register-resident-W epilogue needs ~80 arch-live regs -> structural
// scratch spill that no source-level re-scoping can fix (R9 proved that).
// Relaxing to min-2-waves/EU gives a 256-reg budget; expected allocation
// ~100-140 arch, zero spill. Occupancy: <=128 total -> 2 blocks/CU;
// 129-256 -> 1 block/CU (8 waves) -- either beats spilling by far since the
// per-atom pipeline (16 LDS ops/half, decoupled gathers) has deep ILP.
// Dataflow identical to R9:
//  - GEMM1 swapped (C = w1^T @ rbf^T) so H lands f-major per lane; H staging
//    8x ds_write_b64 + 8x ds_read_b64 per half, XOR swizzle blk^ln^((ln&2)<<3).
//  - GEMM2 normal; W stays entirely in registers; epilogue: lane (q,ln)
//    gathers x[j_{q*4+r}][nt*16+ln] and FMAs against acc[nt][r]; 2-step
//    shfl_xor reduce over q-groups.
//  - b1*log2e folded into GEMM1 C-init, b2 into GEMM2 C-init; log2-domain
//    softplus with scales folded into the bf16 weights.

#define NB     32
#define FD     128
#define RD     64
#define WAVES  8
#define NTILES 2500   // 20000 / 8

#define LOG2E 1.4426950408889634f
#define LN2   0.6931471805599453f

typedef short  short8  __attribute__((ext_vector_type(8)));
typedef float  floatx4 __attribute__((ext_vector_type(4)));
typedef float  floatx2 __attribute__((ext_vector_type(2)));
typedef int    intx4   __attribute__((ext_vector_type(4)));

#define LDS_FENCE() asm volatile("" ::: "memory")  // compiler-only ordering

static __device__ __forceinline__ unsigned pk2(float a, float b) {
  // packed fp32->bf16 RNE (v_cvt_pk_bf16_f32 on gfx950); low 16 = a
  __hip_bfloat162 h = __float22bfloat162_rn(float2{a, b});
  unsigned u;
  __builtin_memcpy(&u, &h, sizeof(u));
  return u;
}

// log2-domain softplus: log2e folded into GEMM1 operands, ln2 into w2.
static __device__ __forceinline__ float sp2(float acc) {
  return __builtin_amdgcn_logf(1.0f + __builtin_amdgcn_exp2f(acc));
}

__global__ __launch_bounds__(512, 2)  // 256-reg budget: no 64/64 split, no spill
void cfconv_kernel(const float* __restrict__ x,
                   const float* __restrict__ rbf,
                   const int*   __restrict__ nbr,
                   const float* __restrict__ w1,
                   const float* __restrict__ b1,
                   const float* __restrict__ w2,
                   const float* __restrict__ b2,
                   float* __restrict__ out) {
  // operand-fragment layout (A and B identical on gfx950 16x16x32):
  // frag[kt*8+nt][lane][j] = M[kt*32 + (lane>>4)*8 + j][nt*16 + (lane&15)]
  __shared__ __align__(16) short w1f[16][64][8];        // 16 KB (w1^T A-frags)
  __shared__ __align__(16) short w2f[32][64][8];        // 32 KB
  // per-wave H band: 16 rows (neighbors) x 32 8B-blocks (128 bf16 f's), swizzled
  __shared__ __align__(16) unsigned long long hb[WAVES][16][32]; // 32 KB -> 80 KB total

  const int tid  = threadIdx.x;
  const int lane = tid & 63;
  const int wv   = tid >> 6;
  const int q    = lane >> 4;   // k-quad (A/B) or row-quad (C)
  const int ln   = lane & 15;   // non-K index inside a 16-tile

  // ---- prepack weights (with scale folding) -> bf16 frags in LDS ----
  for (int i = tid; i < RD * FD; i += 512) {
    int k = i >> 7, n = i & 127, kk = k & 31;
    w1f[(k >> 5) * 8 + (n >> 4)][(kk >> 3) * 16 + (n & 15)][kk & 7] =
        (short)pk2(w1[i] * LOG2E, 0.f);
  }
  for (int i = tid; i < FD * FD; i += 512) {
    int k = i >> 7, n = i & 127, kk = k & 31;
    w2f[(k >> 5) * 8 + (n >> 4)][(kk >> 3) * 16 + (n & 15)][kk & 7] =
        (short)pk2(w2[i] * LN2, 0.f);
  }
  __syncthreads();  // the only barrier; hb use below is wave-private

  unsigned long long (*band)[32] = hb[wv];
  const int swz = ln ^ ((ln & 2) << 3);   // 8B-block XOR swizzle term

  for (int tile = blockIdx.x; tile < NTILES; tile += gridDim.x) {
    const int atom = tile * WAVES + wv;
    const int prow = atom * NB;
    const int* nbp = nbr + prow;

    float o[8];
#pragma unroll
    for (int nt = 0; nt < 8; ++nt) o[nt] = 0.f;

#pragma unroll
    for (int mt = 0; mt < 2; ++mt) {
      // neighbor indices: lane (q,ln) owns n = q*4+r of this half
      const intx4 nbi = *(const intx4*)(nbp + mt * 16 + q * 4);

      floatx4 acc[8];

      { // ---- GEMM1 scope: temporaries die before GEMM2 ----
        // rbf B-frags (B = rbf^T: col n = ln, k = kt*32+q*8+j); streamed once
        const float* src = rbf + (size_t)(prow + mt * 16 + ln) * RD + q * 8;
        short8 bfr[2];
#pragma unroll
        for (int kt = 0; kt < 2; ++kt) {
          floatx4 lo = __builtin_nontemporal_load((const floatx4*)(src + kt * 32));
          floatx4 hi = __builtin_nontemporal_load((const floatx4*)(src + kt * 32 + 4));
          union { short8 s8; unsigned u[4]; } f;
          f.u[0] = pk2(lo[0], lo[1]);
          f.u[1] = pk2(lo[2], lo[3]);
          f.u[2] = pk2(hi[0], hi[1]);
          f.u[3] = pk2(hi[2], hi[3]);
          bfr[kt] = f.s8;
        }

        // C = w1^T @ rbf^T; C-init = b1*log2e (L1-hot reload)
#pragma unroll
        for (int nt = 0; nt < 8; ++nt) {
          floatx4 bv = *(const floatx4*)(b1 + nt * 16 + q * 4);
          acc[nt] = floatx4{bv[0] * LOG2E, bv[1] * LOG2E, bv[2] * LOG2E, bv[3] * LOG2E};
        }
#pragma unroll
        for (int kt = 0; kt < 2; ++kt)
#pragma unroll
          for (int nt = 0; nt < 8; ++nt) {
            short8 afr = *(const short8*)&w1f[kt * 8 + nt][lane][0];
            acc[nt] = __builtin_amdgcn_mfma_f32_16x16x32_bf16(afr, bfr[kt], acc[nt], 0, 0, 0);
          }
      }

      // ---- softplus + pack; lane holds H[n=ln][f=nt*16+q*4+r] -> b64 writes ----
#pragma unroll
      for (int nt = 0; nt < 8; ++nt) {
        unsigned u0 = pk2(sp2(acc[nt][0]), sp2(acc[nt][1]));
        unsigned u1 = pk2(sp2(acc[nt][2]), sp2(acc[nt][3]));
        unsigned long long v = (unsigned long long)u0 | ((unsigned long long)u1 << 32);
        band[ln][(nt * 4 + q) ^ swz] = v;
      }
      LDS_FENCE();  // H writes precede hfr reads in program order

      // pre-issue r=0 gather batch: hides under the LDS reads + MFMA cluster
      const float* xb0 = x + (size_t)nbi[0] * FD + ln;
      float xa[8], xc[8];
#pragma unroll
      for (int nt = 0; nt < 8; ++nt) xa[nt] = xb0[nt * 16];

      // ---- GEMM2: W = H @ (ln2*w2); C-init = b2 splat (L1-hot reload);
      //      hfr streamed per kt (4 regs, short lifetime); W stays in registers.
#pragma unroll
      for (int nt = 0; nt < 8; ++nt) {
        float bb = b2[nt * 16 + ln];
        acc[nt] = floatx4{bb, bb, bb, bb};
      }
#pragma unroll
      for (int kt = 0; kt < 4; ++kt) {
        union { short8 s8; unsigned long long d[2]; } f;
        f.d[0] = band[ln][(kt * 8 + q * 2)     ^ swz];
        f.d[1] = band[ln][(kt * 8 + q * 2 + 1) ^ swz];
        const short8 hk = f.s8;
#pragma unroll
        for (int nt = 0; nt < 8; ++nt) {
          short8 bfr2 = *(const short8*)&w2f[kt * 8 + nt][lane][0];
          acc[nt] = __builtin_amdgcn_mfma_f32_16x16x32_bf16(hk, bfr2, acc[nt], 0, 0, 0);
        }
      }
      LDS_FENCE();  // all band reads precede next half's H overwrite

      // ---- epilogue, 2-deep pipelined: o[nt] += x[j_r][nt*16+ln] * acc[nt][r] ----
      const float* xb1 = x + (size_t)nbi[1] * FD + ln;
#pragma unroll
      for (int nt = 0; nt < 8; ++nt) xc[nt] = xb1[nt * 16];
#pragma unroll
      for (int nt = 0; nt < 8; ++nt) o[nt] = fmaf(xa[nt], acc[nt][0], o[nt]);

      const float* xb2 = x + (size_t)nbi[2] * FD + ln;
#pragma unroll
      for (int nt = 0; nt < 8; ++nt) xa[nt] = xb2[nt * 16];
#pragma unroll
      for (int nt = 0; nt < 8; ++nt) o[nt] = fmaf(xc[nt], acc[nt][1], o[nt]);

      const float* xb3 = x + (size_t)nbi[3] * FD + ln;
#pragma unroll
      for (int nt = 0; nt < 8; ++nt) xc[nt] = xb3[nt * 16];
#pragma unroll
      for (int nt = 0; nt < 8; ++nt) o[nt] = fmaf(xa[nt], acc[nt][2], o[nt]);

#pragma unroll
      for (int nt = 0; nt < 8; ++nt) o[nt] = fmaf(xc[nt], acc[nt][3], o[nt]);
    }

    // ---- reduce over the 4 q-groups (n = q*4+r partials) and store ----
#pragma unroll
    for (int nt = 0; nt < 8; ++nt) {
      o[nt] += __shfl_xor(o[nt], 16);
      o[nt] += __shfl_xor(o[nt], 32);
    }
    // lane (q,ln) stores f = q*32+ln and q*32+16+ln (static indexing only)
    float s0 = o[0], s1 = o[1];
    if (q == 1) { s0 = o[2]; s1 = o[3]; }
    if (q == 2) { s0 = o[4]; s1 = o[5]; }
    if (q == 3) { s0 = o[6]; s1 = o[7]; }
    float* op = out + (size_t)atom * FD + q * 32 + ln;
    __builtin_nontemporal_store(s0, op);
    __builtin_nontemporal_store(s1, op + 16);
  }
}

extern "C" void kernel_launch(void* const* d_in, const int* in_sizes, int n_in,
                              void* d_out, int out_size, void* d_ws, size_t ws_size,
                              hipStream_t stream) {
  const float* x   = (const float*)d_in[0];
  const float* rbf = (const float*)d_in[1];
  const int*   nbr = (const int*)d_in[2];
  const float* w1  = (const float*)d_in[3];
  const float* b1  = (const float*)d_in[4];
  const float* w2  = (const float*)d_in[5];
  const float* b2  = (const float*)d_in[6];
  float* out = (float*)d_out;

  // 80 KB LDS; 500 blocks x 5 tiles each, grid-stride.
  cfconv_kernel<<<dim3(500), dim3(512), 0, stream>>>(x, rbf, nbr, w1, b1, w2, b2, out);
}

// Round 4
// 305.489 us; speedup vs baseline: 1.3696x; 1.0229x over previous
//
#include <hip/hip_runtime.h>
#include <hip/hip_bf16.h>
#include <math.h>

// CFConv: out[a][f] = sum_n x[nbr[a][n]][f] * W[a][n][f]
//   W = (softplus(rbf @ w1 + b1)) @ w2 + b2
// N=20000 atoms, NB=32 neighbors, F=128, RBF=64.
//
// R11 = R10 + software-pipelined HBM loads. R10 (VGPR 104, no-spill) sits at
// 130us with MfmaUtil 9.5%, HBM 24%, VALUBusy 25% -- latency-bound: the 4
// nontemporal rbf b128 loads (~900cy HBM) are issued immediately before their
// consumers every half, fully exposed, and the epilogue's r1 x-gather batch
// (~200-300cy) is exposed after GEMM2.
// Changes:
//  - rbf DOUBLE-BUFFER across halves/tiles: pre[4] floatx4 regs; next half's
//    loads issued right after converting the current half's (cover = GEMM1 +
//    softplus + H-stage + GEMM2 + epilogue instead of 0).
//  - next half's neighbor-index intx4 prefetched at the same point.
//  - x-gather r1 batch moved BEFORE the GEMM2 MFMA cluster (r0+r1 get full
//    MFMA cover; r2/r3 keep 8-FMA cover).
// Register discipline: peak live ~115; MUST stay <=128 total (128 = 4
// waves/SIMD matches the 2-blocks/CU LDS limit; >128 halves occupancy).
// Dataflow otherwise identical to R10 (numerically verified):
//  - GEMM1 swapped (C = w1^T @ rbf^T) so H lands f-major per lane; H staging
//    8x ds_write_b64 + 8x ds_read_b64 per half, XOR swizzle blk^ln^((ln&2)<<3).
//  - GEMM2 normal; W stays entirely in registers; epilogue: lane (q,ln)
//    gathers x[j_{q*4+r}][nt*16+ln] and FMAs against acc[nt][r]; 2-step
//    shfl_xor reduce over q-groups.
//  - b1*log2e folded into GEMM1 C-init, b2 into GEMM2 C-init; log2-domain
//    softplus with scales folded into the bf16 weights.

#define NB     32
#define FD     128
#define RD     64
#define WAVES  8
#define NTILES 2500   // 20000 / 8

#define LOG2E 1.4426950408889634f
#define LN2   0.6931471805599453f

typedef short  short8  __attribute__((ext_vector_type(8)));
typedef float  floatx4 __attribute__((ext_vector_type(4)));
typedef float  floatx2 __attribute__((ext_vector_type(2)));
typedef int    intx4   __attribute__((ext_vector_type(4)));

#define LDS_FENCE() asm volatile("" ::: "memory")  // compiler-only ordering
#define NTLOAD(p) __builtin_nontemporal_load((const floatx4*)(p))

static __device__ __forceinline__ unsigned pk2(float a, float b) {
  // packed fp32->bf16 RNE (v_cvt_pk_bf16_f32 on gfx950); low 16 = a
  __hip_bfloat162 h = __float22bfloat162_rn(float2{a, b});
  unsigned u;
  __builtin_memcpy(&u, &h, sizeof(u));
  return u;
}

// log2-domain softplus: log2e folded into GEMM1 operands, ln2 into w2.
static __device__ __forceinline__ float sp2(float acc) {
  return __builtin_amdgcn_logf(1.0f + __builtin_amdgcn_exp2f(acc));
}

__global__ __launch_bounds__(512, 2)  // 256-reg cap; allocator should land ~120
void cfconv_kernel(const float* __restrict__ x,
                   const float* __restrict__ rbf,
                   const int*   __restrict__ nbr,
                   const float* __restrict__ w1,
                   const float* __restrict__ b1,
                   const float* __restrict__ w2,
                   const float* __restrict__ b2,
                   float* __restrict__ out) {
  // operand-fragment layout (A and B identical on gfx950 16x16x32):
  // frag[kt*8+nt][lane][j] = M[kt*32 + (lane>>4)*8 + j][nt*16 + (lane&15)]
  __shared__ __align__(16) short w1f[16][64][8];        // 16 KB (w1^T A-frags)
  __shared__ __align__(16) short w2f[32][64][8];        // 32 KB
  // per-wave H band: 16 rows (neighbors) x 32 8B-blocks (128 bf16 f's), swizzled
  __shared__ __align__(16) unsigned long long hb[WAVES][16][32]; // 32 KB -> 80 KB total

  const int tid  = threadIdx.x;
  const int lane = tid & 63;
  const int wv   = tid >> 6;
  const int q    = lane >> 4;   // k-quad (A/B) or row-quad (C)
  const int ln   = lane & 15;   // non-K index inside a 16-tile

  // ---- prepack weights (with scale folding) -> bf16 frags in LDS ----
  for (int i = tid; i < RD * FD; i += 512) {
    int k = i >> 7, n = i & 127, kk = k & 31;
    w1f[(k >> 5) * 8 + (n >> 4)][(kk >> 3) * 16 + (n & 15)][kk & 7] =
        (short)pk2(w1[i] * LOG2E, 0.f);
  }
  for (int i = tid; i < FD * FD; i += 512) {
    int k = i >> 7, n = i & 127, kk = k & 31;
    w2f[(k >> 5) * 8 + (n >> 4)][(kk >> 3) * 16 + (n & 15)][kk & 7] =
        (short)pk2(w2[i] * LN2, 0.f);
  }
  __syncthreads();  // the only barrier; hb use below is wave-private

  unsigned long long (*band)[32] = hb[wv];
  const int swz = ln ^ ((ln & 2) << 3);   // 8B-block XOR swizzle term

  // ---- pipeline prologue: issue rbf + nbi loads for (first tile, half 0) ----
  floatx4 pre[4];
  intx4 nbi;
  {
    const int prow0 = (blockIdx.x * WAVES + wv) * NB;
    const float* s = rbf + (size_t)(prow0 + ln) * RD + q * 8;
    pre[0] = NTLOAD(s);      pre[1] = NTLOAD(s + 4);
    pre[2] = NTLOAD(s + 32); pre[3] = NTLOAD(s + 36);
    nbi = *(const intx4*)(nbr + prow0 + q * 4);
  }

  for (int tile = blockIdx.x; tile < NTILES; tile += gridDim.x) {
    const int atom = tile * WAVES + wv;
    const int prow = atom * NB;
    int tnext = tile + gridDim.x;
    if (tnext >= NTILES) tnext = tile;            // dummy (valid addr, unused)
    const int prow_nxt = (tnext * WAVES + wv) * NB;

    float o[8];
#pragma unroll
    for (int nt = 0; nt < 8; ++nt) o[nt] = 0.f;

#pragma unroll
    for (int mt = 0; mt < 2; ++mt) {
      // ---- convert prefetched rbf -> B-frags (B = rbf^T) ----
      short8 bfr[2];
#pragma unroll
      for (int kt = 0; kt < 2; ++kt) {
        floatx4 lo = pre[kt * 2], hi = pre[kt * 2 + 1];
        union { short8 s8; unsigned u[4]; } f;
        f.u[0] = pk2(lo[0], lo[1]);
        f.u[1] = pk2(lo[2], lo[3]);
        f.u[2] = pk2(hi[0], hi[1]);
        f.u[3] = pk2(hi[2], hi[3]);
        bfr[kt] = f.s8;
      }

      // ---- issue NEXT half's rbf + nbi loads (covered by this half's work) ----
      const int nrow = (mt == 0) ? (prow + 16) : prow_nxt;
      {
        const float* s = rbf + (size_t)(nrow + ln) * RD + q * 8;
        pre[0] = NTLOAD(s);      pre[1] = NTLOAD(s + 4);
        pre[2] = NTLOAD(s + 32); pre[3] = NTLOAD(s + 36);
      }
      const intx4 nbi_nxt = *(const intx4*)(nbr + nrow + q * 4);

      // ---- GEMM1: C = w1^T @ rbf^T; C-init = b1*log2e (L1-hot reload) ----
      floatx4 acc[8];
#pragma unroll
      for (int nt = 0; nt < 8; ++nt) {
        floatx4 bv = *(const floatx4*)(b1 + nt * 16 + q * 4);
        acc[nt] = floatx4{bv[0] * LOG2E, bv[1] * LOG2E, bv[2] * LOG2E, bv[3] * LOG2E};
      }
#pragma unroll
      for (int kt = 0; kt < 2; ++kt)
#pragma unroll
        for (int nt = 0; nt < 8; ++nt) {
          short8 afr = *(const short8*)&w1f[kt * 8 + nt][lane][0];
          acc[nt] = __builtin_amdgcn_mfma_f32_16x16x32_bf16(afr, bfr[kt], acc[nt], 0, 0, 0);
        }

      // ---- softplus + pack; lane holds H[n=ln][f=nt*16+q*4+r] -> b64 writes ----
#pragma unroll
      for (int nt = 0; nt < 8; ++nt) {
        unsigned u0 = pk2(sp2(acc[nt][0]), sp2(acc[nt][1]));
        unsigned u1 = pk2(sp2(acc[nt][2]), sp2(acc[nt][3]));
        unsigned long long v = (unsigned long long)u0 | ((unsigned long long)u1 << 32);
        band[ln][(nt * 4 + q) ^ swz] = v;
      }
      LDS_FENCE();  // H writes precede hfr reads in program order

      // ---- x gathers r0+r1 issued before GEMM2: full MFMA-cluster cover ----
      const float* xb0 = x + (size_t)nbi[0] * FD + ln;
      const float* xb1 = x + (size_t)nbi[1] * FD + ln;
      float xa[8], xc[8];
#pragma unroll
      for (int nt = 0; nt < 8; ++nt) xa[nt] = xb0[nt * 16];
#pragma unroll
      for (int nt = 0; nt < 8; ++nt) xc[nt] = xb1[nt * 16];

      // ---- GEMM2: W = H @ (ln2*w2); C-init = b2 splat (L1-hot reload);
      //      hfr streamed per kt; W stays in registers.
#pragma unroll
      for (int nt = 0; nt < 8; ++nt) {
        float bb = b2[nt * 16 + ln];
        acc[nt] = floatx4{bb, bb, bb, bb};
      }
#pragma unroll
      for (int kt = 0; kt < 4; ++kt) {
        union { short8 s8; unsigned long long d[2]; } f;
        f.d[0] = band[ln][(kt * 8 + q * 2)     ^ swz];
        f.d[1] = band[ln][(kt * 8 + q * 2 + 1) ^ swz];
        const short8 hk = f.s8;
#pragma unroll
        for (int nt = 0; nt < 8; ++nt) {
          short8 bfr2 = *(const short8*)&w2f[kt * 8 + nt][lane][0];
          acc[nt] = __builtin_amdgcn_mfma_f32_16x16x32_bf16(hk, bfr2, acc[nt], 0, 0, 0);
        }
      }
      LDS_FENCE();  // all band reads precede next half's H overwrite

      // ---- epilogue: o[nt] += x[j_r][nt*16+ln] * acc[nt][r], 2-deep rotate ----
#pragma unroll
      for (int nt = 0; nt < 8; ++nt) o[nt] = fmaf(xa[nt], acc[nt][0], o[nt]);
      const float* xb2 = x + (size_t)nbi[2] * FD + ln;
#pragma unroll
      for (int nt = 0; nt < 8; ++nt) xa[nt] = xb2[nt * 16];

#pragma unroll
      for (int nt = 0; nt < 8; ++nt) o[nt] = fmaf(xc[nt], acc[nt][1], o[nt]);
      const float* xb3 = x + (size_t)nbi[3] * FD + ln;
#pragma unroll
      for (int nt = 0; nt < 8; ++nt) xc[nt] = xb3[nt * 16];

#pragma unroll
      for (int nt = 0; nt < 8; ++nt) o[nt] = fmaf(xa[nt], acc[nt][2], o[nt]);
#pragma unroll
      for (int nt = 0; nt < 8; ++nt) o[nt] = fmaf(xc[nt], acc[nt][3], o[nt]);

      nbi = nbi_nxt;  // rotate neighbor indices into next half
    }

    // ---- reduce over the 4 q-groups (n = q*4+r partials) and store ----
#pragma unroll
    for (int nt = 0; nt < 8; ++nt) {
      o[nt] += __shfl_xor(o[nt], 16);
      o[nt] += __shfl_xor(o[nt], 32);
    }
    // lane (q,ln) stores f = q*32+ln and q*32+16+ln (static indexing only)
    float s0 = o[0], s1 = o[1];
    if (q == 1) { s0 = o[2]; s1 = o[3]; }
    if (q == 2) { s0 = o[4]; s1 = o[5]; }
    if (q == 3) { s0 = o[6]; s1 = o[7]; }
    float* op = out + (size_t)atom * FD + q * 32 + ln;
    __builtin_nontemporal_store(s0, op);
    __builtin_nontemporal_store(s1, op + 16);
  }
}

extern "C" void kernel_launch(void* const* d_in, const int* in_sizes, int n_in,
                              void* d_out, int out_size, void* d_ws, size_t ws_size,
                              hipStream_t stream) {
  const float* x   = (const float*)d_in[0];
  const float* rbf = (const float*)d_in[1];
  const int*   nbr = (const int*)d_in[2];
  const float* w1  = (const float*)d_in[3];
  const float* b1  = (const float*)d_in[4];
  const float* w2  = (const float*)d_in[5];
  const float* b2  = (const float*)d_in[6];
  float* out = (float*)d_out;

  // 80 KB LDS -> 2 blocks/CU; 500 blocks x 5 tiles each, grid-stride.
  cfconv_kernel<<<dim3(500), dim3(512), 0, stream>>>(x, rbf, nbr, w1, b1, w2, b2, out);
}